// Round 14
// baseline (4124.770 us; speedup 1.0000x reference)
//
#include <hip/hip_runtime.h>
#include <hip/hip_bf16.h>
#include <math.h>

#define NNODES 50000
#define NEDGES 800000

static inline int cdiv(int a, int b) { return (a + b - 1) / b; }

// ================= CSR build (once per call; graph shared by all layers) =================

__global__ void count_deg(const int* __restrict__ dst, int* __restrict__ deg) {
    int e = blockIdx.x * blockDim.x + threadIdx.x;
    if (e < NEDGES) atomicAdd(&deg[dst[e]], 1);
}

// single-block exclusive scan, 4 elems/thread -> rowptr[0..N], cursor copy
__global__ void scan_rowptr(const int* __restrict__ deg, int* __restrict__ rowptr,
                            int* __restrict__ cursor) {
    __shared__ int wsum[16];
    __shared__ int wpre[16];
    const int tid = threadIdx.x;
    const int lane = tid & 63, wid = tid >> 6;
    int carry = 0;
    const int ntiles = (NNODES + 4095) / 4096;
    for (int t = 0; t < ntiles; t++) {
        int i0 = t * 4096 + tid * 4;
        int4 v = make_int4(0, 0, 0, 0);
        if (i0 < NNODES) v = *(const int4*)&deg[i0];   // NNODES % 4 == 0
        int lsum = v.x + v.y + v.z + v.w;
        int x = lsum;
#pragma unroll
        for (int off = 1; off < 64; off <<= 1) {
            int y = __shfl_up(x, off);
            if (lane >= off) x += y;
        }
        if (lane == 63) wsum[wid] = x;
        __syncthreads();
        if (wid == 0) {
            int w = (lane < 16) ? wsum[lane] : 0;
            int xs = w;
#pragma unroll
            for (int off = 1; off < 16; off <<= 1) {
                int y = __shfl_up(xs, off);
                if (lane >= off) xs += y;
            }
            if (lane < 16) wpre[lane] = xs - w;   // exclusive wave prefix
        }
        __syncthreads();
        int excl = carry + wpre[wid] + x - lsum;
        if (i0 < NNODES) {
            int4 r;
            r.x = excl; r.y = r.x + v.x; r.z = r.y + v.y; r.w = r.z + v.z;
            *(int4*)&rowptr[i0] = r;
            *(int4*)&cursor[i0] = r;
        }
        carry += wpre[15] + wsum[15];
        __syncthreads();
    }
    if (tid == 0) rowptr[NNODES] = carry;
}

// ====== register-tiled fp32 GEMM body (x @ W) + attention projections; feat bf16 ======
// 256 threads, BMxDOUT tile, BK=32, 4x8 register tile/thread, 25KB LDS.
template <int BM, int DOUT, int H>
__device__ __forceinline__ void gemm_attn_body(
    int bid, const float* __restrict__ x, const float* __restrict__ W,
    const float* __restrict__ al, const float* __restrict__ ar,
    __hip_bfloat16* __restrict__ feat, float* __restrict__ el,
    float* __restrict__ er) {
    constexpr int BK = 32;
    constexpr int NC = 8;                 // cols per thread
    constexpr int CG = DOUT / NC;         // col groups (16 or 8)
    constexpr int NG = 256 / CG;          // node groups (16 or 32)
    constexpr int NT = BM / NG;           // nodes per thread (4)
    constexpr int D = DOUT / H;           // dims per head
    constexpr int CPH = D / NC;           // col-groups per head (4 or 8)
    constexpr int XP = BM + 4;            // padded x_t stride
    static_assert(NT == 4, "tile assumes 4 nodes/thread");

    __shared__ float xs[BK][XP];
    __shared__ float ws[BK][DOUT];

    const int t = threadIdx.x;
    const int node0 = bid * BM;
    const int cg = t % CG, ng = t / CG;
    const int c0 = cg * NC, n0 = ng * NT;

    float acc[NT][NC];
#pragma unroll
    for (int i = 0; i < NT; i++)
#pragma unroll
        for (int j = 0; j < NC; j++) acc[i][j] = 0.f;

    for (int k0 = 0; k0 < 128; k0 += BK) {
        for (int i = t * 4; i < BK * DOUT; i += 256 * 4) {
            int kk = i / DOUT, c = i % DOUT;
            *(float4*)&ws[kk][c] = *(const float4*)&W[(k0 + kk) * DOUT + c];
        }
        for (int i = t; i < BK * BM; i += 256) {
            int kk = i & (BK - 1), nd = i >> 5;
            int node = node0 + nd;
            xs[kk][nd] = (node < NNODES) ? x[node * 128 + k0 + kk] : 0.f;
        }
        __syncthreads();
        for (int k = 0; k < BK; k++) {
            const float4 wa = *(const float4*)&ws[k][c0];
            const float4 wb = *(const float4*)&ws[k][c0 + 4];
            float wv[NC] = {wa.x, wa.y, wa.z, wa.w, wb.x, wb.y, wb.z, wb.w};
            const float4 xv = *(const float4*)&xs[k][n0];
            float xvv[4] = {xv.x, xv.y, xv.z, xv.w};
#pragma unroll
            for (int ii = 0; ii < 4; ii++)
#pragma unroll
                for (int q = 0; q < NC; q++)
                    acc[ii][q] += xvv[ii] * wv[q];
        }
        __syncthreads();
    }

    const float4 ala = *(const float4*)&al[c0];
    const float4 alb = *(const float4*)&al[c0 + 4];
    const float4 ara = *(const float4*)&ar[c0];
    const float4 arb = *(const float4*)&ar[c0 + 4];
    const float alv[NC] = {ala.x, ala.y, ala.z, ala.w, alb.x, alb.y, alb.z, alb.w};
    const float arv[NC] = {ara.x, ara.y, ara.z, ara.w, arb.x, arb.y, arb.z, arb.w};
    const int head = c0 / D;
#pragma unroll
    for (int i = 0; i < NT; i++) {
        const int node = node0 + n0 + i;
        float pl = 0.f, pr = 0.f;
        if (node < NNODES) {
            ushort4 u0, u1;
            u0.x = __bfloat16_as_ushort(__float2bfloat16(acc[i][0]));
            u0.y = __bfloat16_as_ushort(__float2bfloat16(acc[i][1]));
            u0.z = __bfloat16_as_ushort(__float2bfloat16(acc[i][2]));
            u0.w = __bfloat16_as_ushort(__float2bfloat16(acc[i][3]));
            u1.x = __bfloat16_as_ushort(__float2bfloat16(acc[i][4]));
            u1.y = __bfloat16_as_ushort(__float2bfloat16(acc[i][5]));
            u1.z = __bfloat16_as_ushort(__float2bfloat16(acc[i][6]));
            u1.w = __bfloat16_as_ushort(__float2bfloat16(acc[i][7]));
            *(ushort4*)&feat[node * DOUT + c0] = u0;
            *(ushort4*)&feat[node * DOUT + c0 + 4] = u1;
        }
#pragma unroll
        for (int q = 0; q < NC; q++) {
            pl += acc[i][q] * alv[q];
            pr += acc[i][q] * arv[q];
        }
#pragma unroll
        for (int off = CPH / 2; off > 0; off >>= 1) {
            pl += __shfl_xor(pl, off);
            pr += __shfl_xor(pr, off);
        }
        if ((cg % CPH) == 0 && node < NNODES) {
            el[node * H + head] = pl;
            er[node * H + head] = pr;
        }
    }
}

template <int BM, int DOUT, int H>
__global__ __launch_bounds__(256) void gemm_attn_rt2(
    const float* __restrict__ x, const float* __restrict__ W,
    const float* __restrict__ al, const float* __restrict__ ar,
    __hip_bfloat16* __restrict__ feat, float* __restrict__ el,
    float* __restrict__ er) {
    gemm_attn_body<BM, DOUT, H>(blockIdx.x, x, W, al, ar, feat, el, er);
}

// ====== fused: scatter_src (atomic/latency-bound, blocks [0,SCAT)) ∥ layer-1 GEMM
// (VALU-bound, blocks [SCAT, SCAT+GEMM)). Disjoint data, no ordering dependency;
// the GEMM hides under the scatter's atomic latency.
#define SCAT_BLOCKS ((NEDGES + 255) / 256)
#define GEMM1_BLOCKS ((NNODES + 63) / 64)

__global__ __launch_bounds__(256) void scatter_plus_gemm1(
    const int* __restrict__ src, const int* __restrict__ dst,
    int* __restrict__ cursor, int* __restrict__ csr_src,
    const float* __restrict__ x, const float* __restrict__ W,
    const float* __restrict__ al, const float* __restrict__ ar,
    __hip_bfloat16* __restrict__ feat, float* __restrict__ el,
    float* __restrict__ er) {
    if (blockIdx.x < SCAT_BLOCKS) {
        int e = blockIdx.x * 256 + threadIdx.x;
        if (e < NEDGES) {
            int pos = atomicAdd(&cursor[dst[e]], 1);
            csr_src[pos] = src[e];
        }
    } else {
        gemm_attn_body<64, 128, 4>(blockIdx.x - SCAT_BLOCKS, x, W, al, ar, feat, el, er);
    }
}

// ========== per-node softmax + aggregation (no atomics, 4x unroll, fp32 out) ==========
template <int DOUT, int H>
__global__ __launch_bounds__(256) void node_aggregate3(
    const int* __restrict__ rowptr, const int* __restrict__ csr_src,
    const float* __restrict__ el, const float* __restrict__ er,
    const __hip_bfloat16* __restrict__ feat, const float* __restrict__ b,
    float* __restrict__ xout, int do_elu) {
    constexpr int D = DOUT / H;        // dims per head
    constexpr int PL = DOUT / 64;      // dims per lane (2 or 1)
    const int lane = threadIdx.x & 63;
    const int wid = threadIdx.x >> 6;
    const int n = blockIdx.x * 4 + wid;
    if (n >= NNODES) return;
    const int base = rowptr[n];
    const int deg = rowptr[n + 1] - base;

    const int h = (lane * PL) / D;     // head owning this lane's dims
    const float erh = er[n * H + h];
    const int* cs = &csr_src[base];

    float s = 0.f;
    float a0 = 0.f, a1 = 0.f;

    int j = 0;
    for (; j + 3 < deg; j += 4) {
        int sn0 = cs[j], sn1 = cs[j + 1], sn2 = cs[j + 2], sn3 = cs[j + 3];
        float e0 = el[sn0 * H + h] + erh;
        float e1 = el[sn1 * H + h] + erh;
        float e2 = el[sn2 * H + h] + erh;
        float e3 = el[sn3 * H + h] + erh;
        e0 = e0 > 0.f ? e0 : 0.2f * e0;
        e1 = e1 > 0.f ? e1 : 0.2f * e1;
        e2 = e2 > 0.f ? e2 : 0.2f * e2;
        e3 = e3 > 0.f ? e3 : 0.2f * e3;
        float p0 = __expf(e0), p1 = __expf(e1), p2 = __expf(e2), p3 = __expf(e3);
        s += (p0 + p1) + (p2 + p3);
        if constexpr (PL == 2) {
            float2 f0 = __bfloat1622float2(*(const __hip_bfloat162*)&feat[sn0 * DOUT + lane * 2]);
            float2 f1 = __bfloat1622float2(*(const __hip_bfloat162*)&feat[sn1 * DOUT + lane * 2]);
            float2 f2 = __bfloat1622float2(*(const __hip_bfloat162*)&feat[sn2 * DOUT + lane * 2]);
            float2 f3 = __bfloat1622float2(*(const __hip_bfloat162*)&feat[sn3 * DOUT + lane * 2]);
            a0 += p0 * f0.x + p1 * f1.x + p2 * f2.x + p3 * f3.x;
            a1 += p0 * f0.y + p1 * f1.y + p2 * f2.y + p3 * f3.y;
        } else {
            a0 += p0 * __bfloat162float(feat[sn0 * DOUT + lane])
                + p1 * __bfloat162float(feat[sn1 * DOUT + lane])
                + p2 * __bfloat162float(feat[sn2 * DOUT + lane])
                + p3 * __bfloat162float(feat[sn3 * DOUT + lane]);
        }
    }
    for (; j < deg; j++) {
        int sn0 = cs[j];
        float e0 = el[sn0 * H + h] + erh;
        e0 = e0 > 0.f ? e0 : 0.2f * e0;
        float p0 = __expf(e0);
        s += p0;
        if constexpr (PL == 2) {
            float2 f0 = __bfloat1622float2(*(const __hip_bfloat162*)&feat[sn0 * DOUT + lane * 2]);
            a0 += p0 * f0.x;
            a1 += p0 * f0.y;
        } else {
            a0 += p0 * __bfloat162float(feat[sn0 * DOUT + lane]);
        }
    }

    const float inv = (s > 0.f) ? 1.f / s : 0.f;
    if constexpr (PL == 2) {
        float v0 = a0 * inv + b[lane * 2];
        float v1 = a1 * inv + b[lane * 2 + 1];
        if (do_elu) {
            v0 = v0 > 0.f ? v0 : expm1f(v0);
            v1 = v1 > 0.f ? v1 : expm1f(v1);
        }
        float2 o = {v0, v1};
        *(float2*)&xout[n * DOUT + lane * 2] = o;
    } else {
        float v0 = a0 * inv + b[lane];
        if (do_elu) v0 = v0 > 0.f ? v0 : expm1f(v0);
        xout[n * DOUT + lane] = v0;
    }
}

// ================= launch =================
extern "C" void kernel_launch(void* const* d_in, const int* in_sizes, int n_in,
                              void* d_out, int out_size, void* d_ws, size_t ws_size,
                              hipStream_t stream) {
    const float* h   = (const float*)d_in[0];
    const int*   src = (const int*)d_in[1];
    const int*   dst = (const int*)d_in[2];
    const float* W1  = (const float*)d_in[3];
    const float* al1 = (const float*)d_in[4];
    const float* ar1 = (const float*)d_in[5];
    const float* b1  = (const float*)d_in[6];
    const float* W2  = (const float*)d_in[7];
    const float* al2 = (const float*)d_in[8];
    const float* ar2 = (const float*)d_in[9];
    const float* b2  = (const float*)d_in[10];
    const float* W3  = (const float*)d_in[11];
    const float* al3 = (const float*)d_in[12];
    const float* ar3 = (const float*)d_in[13];
    const float* b3  = (const float*)d_in[14];

    char* w = (char*)d_ws;
    __hip_bfloat16* feat = (__hip_bfloat16*)w;  w += (size_t)NNODES * 128 * 2;
    float* x2 = (float*)w;                      w += (size_t)NNODES * 128 * 4;
    float* x3 = (float*)w;                      w += (size_t)NNODES * 128 * 4;
    float* el = (float*)w;                      w += (size_t)NNODES * 4 * 4;
    float* er = (float*)w;                      w += (size_t)NNODES * 4 * 4;
    int* deg     = (int*)w;                     w += (size_t)NNODES * 4;
    int* rowptr  = (int*)w;                     w += (size_t)(NNODES + 4) * 4;
    int* cursor  = (int*)w;                     w += (size_t)NNODES * 4;
    int* csr_src = (int*)w;

    const dim3 B(256);

    // ---- CSR build (graph is layer-invariant); layer-1 GEMM fused with scatter ----
    hipMemsetAsync(deg, 0, (size_t)NNODES * 4, stream);
    count_deg<<<cdiv(NEDGES, 256), B, 0, stream>>>(dst, deg);
    scan_rowptr<<<1, 1024, 0, stream>>>(deg, rowptr, cursor);
    scatter_plus_gemm1<<<SCAT_BLOCKS + GEMM1_BLOCKS, B, 0, stream>>>(
        src, dst, cursor, csr_src, h, W1, al1, ar1, feat, el, er);

    // ---- layer 1 aggregation (H=4, D=32, DOUT=128) ----
    node_aggregate3<128, 4><<<cdiv(NNODES, 4), B, 0, stream>>>(rowptr, csr_src, el, er, feat, b1, x2, 1);

    // ---- layer 2 (H=4, D=32, DOUT=128) ----
    gemm_attn_rt2<64, 128, 4><<<cdiv(NNODES, 64), B, 0, stream>>>(x2, W2, al2, ar2, feat, el, er);
    node_aggregate3<128, 4><<<cdiv(NNODES, 4), B, 0, stream>>>(rowptr, csr_src, el, er, feat, b2, x3, 1);

    // ---- layer 3 (H=1, D=64, DOUT=64) ----
    gemm_attn_rt2<128, 64, 1><<<cdiv(NNODES, 128), B, 0, stream>>>(x3, W3, al3, ar3, feat, el, er);
    node_aggregate3<64, 1><<<cdiv(NNODES, 4), B, 0, stream>>>(rowptr, csr_src, el, er, feat, b3, (float*)d_out, 0);
}

// Round 15
// 405.527 us; speedup vs baseline: 10.1714x; 10.1714x over previous
//
#include <hip/hip_runtime.h>
#include <hip/hip_bf16.h>
#include <math.h>

#define NNODES 50000
#define NEDGES 800000

static inline int cdiv(int a, int b) { return (a + b - 1) / b; }

// ================= CSR build (once per call; graph shared by all layers) =================

__global__ void count_deg(const int* __restrict__ dst, int* __restrict__ deg) {
    int e = blockIdx.x * blockDim.x + threadIdx.x;
    if (e < NEDGES) atomicAdd(&deg[dst[e]], 1);
}

// single-block exclusive scan, 4 elems/thread -> rowptr[0..N], cursor copy
__global__ void scan_rowptr(const int* __restrict__ deg, int* __restrict__ rowptr,
                            int* __restrict__ cursor) {
    __shared__ int wsum[16];
    __shared__ int wpre[16];
    const int tid = threadIdx.x;
    const int lane = tid & 63, wid = tid >> 6;
    int carry = 0;
    const int ntiles = (NNODES + 4095) / 4096;
    for (int t = 0; t < ntiles; t++) {
        int i0 = t * 4096 + tid * 4;
        int4 v = make_int4(0, 0, 0, 0);
        if (i0 < NNODES) v = *(const int4*)&deg[i0];   // NNODES % 4 == 0
        int lsum = v.x + v.y + v.z + v.w;
        int x = lsum;
#pragma unroll
        for (int off = 1; off < 64; off <<= 1) {
            int y = __shfl_up(x, off);
            if (lane >= off) x += y;
        }
        if (lane == 63) wsum[wid] = x;
        __syncthreads();
        if (wid == 0) {
            int w = (lane < 16) ? wsum[lane] : 0;
            int xs = w;
#pragma unroll
            for (int off = 1; off < 16; off <<= 1) {
                int y = __shfl_up(xs, off);
                if (lane >= off) xs += y;
            }
            if (lane < 16) wpre[lane] = xs - w;   // exclusive wave prefix
        }
        __syncthreads();
        int excl = carry + wpre[wid] + x - lsum;
        if (i0 < NNODES) {
            int4 r;
            r.x = excl; r.y = r.x + v.x; r.z = r.y + v.y; r.w = r.z + v.z;
            *(int4*)&rowptr[i0] = r;
            *(int4*)&cursor[i0] = r;
        }
        carry += wpre[15] + wsum[15];
        __syncthreads();
    }
    if (tid == 0) rowptr[NNODES] = carry;
}

__global__ void scatter_src(const int* __restrict__ src, const int* __restrict__ dst,
                            int* __restrict__ cursor, int* __restrict__ csr_src) {
    int e = blockIdx.x * blockDim.x + threadIdx.x;
    if (e < NEDGES) {
        int pos = atomicAdd(&cursor[dst[e]], 1);
        csr_src[pos] = src[e];
    }
}

// ====== register-tiled fp32 GEMM (x @ W) + attention projections; feat written bf16 ======
// 256 threads, BMxDOUT tile, BK=32, NTx8 register tile/thread.
// BM=64 everywhere: grid 782 = ~3 blocks/CU (BM=128 was 391 blocks -> 13% occupancy,
// latency-bound, round-11 counters). NT=4 for DOUT=128, NT=2 for DOUT=64.
// NOTE (round 14): do NOT inline this body into a branchy fused kernel — the register
// allocator blew up to 256 VGPR + 2.6 GB spill traffic (10x regression).
template <int BM, int DOUT, int H>
__global__ __launch_bounds__(256) void gemm_attn_rt2(
    const float* __restrict__ x, const float* __restrict__ W,
    const float* __restrict__ al, const float* __restrict__ ar,
    __hip_bfloat16* __restrict__ feat, float* __restrict__ el,
    float* __restrict__ er) {
    constexpr int BK = 32;
    constexpr int NC = 8;                 // cols per thread
    constexpr int CG = DOUT / NC;         // col groups (16 or 8)
    constexpr int NG = 256 / CG;          // node groups (16 or 32)
    constexpr int NT = BM / NG;           // nodes per thread (4 or 2)
    constexpr int D = DOUT / H;           // dims per head
    constexpr int CPH = D / NC;           // col-groups per head (4 or 8)
    constexpr int XP = BM + 4;            // padded x_t stride
    static_assert(NT == 4 || NT == 2, "tile assumes 2 or 4 nodes/thread");

    __shared__ float xs[BK][XP];
    __shared__ float ws[BK][DOUT];

    const int t = threadIdx.x;
    const int node0 = blockIdx.x * BM;
    const int cg = t % CG, ng = t / CG;
    const int c0 = cg * NC, n0 = ng * NT;

    float acc[NT][NC];
#pragma unroll
    for (int i = 0; i < NT; i++)
#pragma unroll
        for (int j = 0; j < NC; j++) acc[i][j] = 0.f;

    for (int k0 = 0; k0 < 128; k0 += BK) {
        // stage W k-slice (coalesced float4)
        for (int i = t * 4; i < BK * DOUT; i += 256 * 4) {
            int kk = i / DOUT, c = i % DOUT;
            *(float4*)&ws[kk][c] = *(const float4*)&W[(k0 + kk) * DOUT + c];
        }
        // stage x transposed (coalesced global read)
        for (int i = t; i < BK * BM; i += 256) {
            int kk = i & (BK - 1), nd = i >> 5;
            int node = node0 + nd;
            xs[kk][nd] = (node < NNODES) ? x[node * 128 + k0 + kk] : 0.f;
        }
        __syncthreads();
        for (int k = 0; k < BK; k++) {
            const float4 wa = *(const float4*)&ws[k][c0];
            const float4 wb = *(const float4*)&ws[k][c0 + 4];
            float wv[NC] = {wa.x, wa.y, wa.z, wa.w, wb.x, wb.y, wb.z, wb.w};
            float xvv[NT];
            if constexpr (NT == 4) {
                const float4 xv = *(const float4*)&xs[k][n0];
                xvv[0] = xv.x; xvv[1] = xv.y; xvv[2] = xv.z; xvv[3] = xv.w;
            } else {
                const float2 xv = *(const float2*)&xs[k][n0];
                xvv[0] = xv.x; xvv[1] = xv.y;
            }
#pragma unroll
            for (int ii = 0; ii < NT; ii++)
#pragma unroll
                for (int q = 0; q < NC; q++)
                    acc[ii][q] += xvv[ii] * wv[q];
        }
        __syncthreads();
    }

    // epilogue: feat (bf16x8), el/er via shfl-reduce over the head's col-groups
    const float4 ala = *(const float4*)&al[c0];
    const float4 alb = *(const float4*)&al[c0 + 4];
    const float4 ara = *(const float4*)&ar[c0];
    const float4 arb = *(const float4*)&ar[c0 + 4];
    const float alv[NC] = {ala.x, ala.y, ala.z, ala.w, alb.x, alb.y, alb.z, alb.w};
    const float arv[NC] = {ara.x, ara.y, ara.z, ara.w, arb.x, arb.y, arb.z, arb.w};
    const int head = c0 / D;
#pragma unroll
    for (int i = 0; i < NT; i++) {
        const int node = node0 + n0 + i;
        float pl = 0.f, pr = 0.f;
        if (node < NNODES) {
            ushort4 u0, u1;
            u0.x = __bfloat16_as_ushort(__float2bfloat16(acc[i][0]));
            u0.y = __bfloat16_as_ushort(__float2bfloat16(acc[i][1]));
            u0.z = __bfloat16_as_ushort(__float2bfloat16(acc[i][2]));
            u0.w = __bfloat16_as_ushort(__float2bfloat16(acc[i][3]));
            u1.x = __bfloat16_as_ushort(__float2bfloat16(acc[i][4]));
            u1.y = __bfloat16_as_ushort(__float2bfloat16(acc[i][5]));
            u1.z = __bfloat16_as_ushort(__float2bfloat16(acc[i][6]));
            u1.w = __bfloat16_as_ushort(__float2bfloat16(acc[i][7]));
            *(ushort4*)&feat[node * DOUT + c0] = u0;
            *(ushort4*)&feat[node * DOUT + c0 + 4] = u1;
        }
#pragma unroll
        for (int q = 0; q < NC; q++) {
            pl += acc[i][q] * alv[q];
            pr += acc[i][q] * arv[q];
        }
#pragma unroll
        for (int off = CPH / 2; off > 0; off >>= 1) {
            pl += __shfl_xor(pl, off);
            pr += __shfl_xor(pr, off);
        }
        if ((cg % CPH) == 0 && node < NNODES) {
            el[node * H + head] = pl;
            er[node * H + head] = pr;
        }
    }
}

// ========== per-node softmax + aggregation (no atomics, 4x unroll, fp32 out) ==========
template <int DOUT, int H>
__global__ __launch_bounds__(256) void node_aggregate3(
    const int* __restrict__ rowptr, const int* __restrict__ csr_src,
    const float* __restrict__ el, const float* __restrict__ er,
    const __hip_bfloat16* __restrict__ feat, const float* __restrict__ b,
    float* __restrict__ xout, int do_elu) {
    constexpr int D = DOUT / H;        // dims per head
    constexpr int PL = DOUT / 64;      // dims per lane (2 or 1)
    const int lane = threadIdx.x & 63;
    const int wid = threadIdx.x >> 6;
    const int n = blockIdx.x * 4 + wid;
    if (n >= NNODES) return;
    const int base = rowptr[n];
    const int deg = rowptr[n + 1] - base;

    const int h = (lane * PL) / D;     // head owning this lane's dims
    const float erh = er[n * H + h];
    const int* cs = &csr_src[base];

    float s = 0.f;
    float a0 = 0.f, a1 = 0.f;

    int j = 0;
    for (; j + 3 < deg; j += 4) {
        int sn0 = cs[j], sn1 = cs[j + 1], sn2 = cs[j + 2], sn3 = cs[j + 3];
        float e0 = el[sn0 * H + h] + erh;
        float e1 = el[sn1 * H + h] + erh;
        float e2 = el[sn2 * H + h] + erh;
        float e3 = el[sn3 * H + h] + erh;
        e0 = e0 > 0.f ? e0 : 0.2f * e0;
        e1 = e1 > 0.f ? e1 : 0.2f * e1;
        e2 = e2 > 0.f ? e2 : 0.2f * e2;
        e3 = e3 > 0.f ? e3 : 0.2f * e3;
        float p0 = __expf(e0), p1 = __expf(e1), p2 = __expf(e2), p3 = __expf(e3);
        s += (p0 + p1) + (p2 + p3);
        if constexpr (PL == 2) {
            float2 f0 = __bfloat1622float2(*(const __hip_bfloat162*)&feat[sn0 * DOUT + lane * 2]);
            float2 f1 = __bfloat1622float2(*(const __hip_bfloat162*)&feat[sn1 * DOUT + lane * 2]);
            float2 f2 = __bfloat1622float2(*(const __hip_bfloat162*)&feat[sn2 * DOUT + lane * 2]);
            float2 f3 = __bfloat1622float2(*(const __hip_bfloat162*)&feat[sn3 * DOUT + lane * 2]);
            a0 += p0 * f0.x + p1 * f1.x + p2 * f2.x + p3 * f3.x;
            a1 += p0 * f0.y + p1 * f1.y + p2 * f2.y + p3 * f3.y;
        } else {
            a0 += p0 * __bfloat162float(feat[sn0 * DOUT + lane])
                + p1 * __bfloat162float(feat[sn1 * DOUT + lane])
                + p2 * __bfloat162float(feat[sn2 * DOUT + lane])
                + p3 * __bfloat162float(feat[sn3 * DOUT + lane]);
        }
    }
    for (; j < deg; j++) {
        int sn0 = cs[j];
        float e0 = el[sn0 * H + h] + erh;
        e0 = e0 > 0.f ? e0 : 0.2f * e0;
        float p0 = __expf(e0);
        s += p0;
        if constexpr (PL == 2) {
            float2 f0 = __bfloat1622float2(*(const __hip_bfloat162*)&feat[sn0 * DOUT + lane * 2]);
            a0 += p0 * f0.x;
            a1 += p0 * f0.y;
        } else {
            a0 += p0 * __bfloat162float(feat[sn0 * DOUT + lane]);
        }
    }

    const float inv = (s > 0.f) ? 1.f / s : 0.f;
    if constexpr (PL == 2) {
        float v0 = a0 * inv + b[lane * 2];
        float v1 = a1 * inv + b[lane * 2 + 1];
        if (do_elu) {
            v0 = v0 > 0.f ? v0 : expm1f(v0);
            v1 = v1 > 0.f ? v1 : expm1f(v1);
        }
        float2 o = {v0, v1};
        *(float2*)&xout[n * DOUT + lane * 2] = o;
    } else {
        float v0 = a0 * inv + b[lane];
        if (do_elu) v0 = v0 > 0.f ? v0 : expm1f(v0);
        xout[n * DOUT + lane] = v0;
    }
}

// ================= launch =================
extern "C" void kernel_launch(void* const* d_in, const int* in_sizes, int n_in,
                              void* d_out, int out_size, void* d_ws, size_t ws_size,
                              hipStream_t stream) {
    const float* h   = (const float*)d_in[0];
    const int*   src = (const int*)d_in[1];
    const int*   dst = (const int*)d_in[2];
    const float* W1  = (const float*)d_in[3];
    const float* al1 = (const float*)d_in[4];
    const float* ar1 = (const float*)d_in[5];
    const float* b1  = (const float*)d_in[6];
    const float* W2  = (const float*)d_in[7];
    const float* al2 = (const float*)d_in[8];
    const float* ar2 = (const float*)d_in[9];
    const float* b2  = (const float*)d_in[10];
    const float* W3  = (const float*)d_in[11];
    const float* al3 = (const float*)d_in[12];
    const float* ar3 = (const float*)d_in[13];
    const float* b3  = (const float*)d_in[14];

    char* w = (char*)d_ws;
    __hip_bfloat16* feat = (__hip_bfloat16*)w;  w += (size_t)NNODES * 128 * 2;
    float* x2 = (float*)w;                      w += (size_t)NNODES * 128 * 4;
    float* x3 = (float*)w;                      w += (size_t)NNODES * 128 * 4;
    float* el = (float*)w;                      w += (size_t)NNODES * 4 * 4;
    float* er = (float*)w;                      w += (size_t)NNODES * 4 * 4;
    int* deg     = (int*)w;                     w += (size_t)NNODES * 4;
    int* rowptr  = (int*)w;                     w += (size_t)(NNODES + 4) * 4;
    int* cursor  = (int*)w;                     w += (size_t)NNODES * 4;
    int* csr_src = (int*)w;

    const dim3 B(256);

    // ---- CSR build (graph is layer-invariant) ----
    hipMemsetAsync(deg, 0, (size_t)NNODES * 4, stream);
    count_deg<<<cdiv(NEDGES, 256), B, 0, stream>>>(dst, deg);
    scan_rowptr<<<1, 1024, 0, stream>>>(deg, rowptr, cursor);
    scatter_src<<<cdiv(NEDGES, 256), B, 0, stream>>>(src, dst, cursor, csr_src);

    // ---- layer 1 (H=4, D=32, DOUT=128) ----
    gemm_attn_rt2<64, 128, 4><<<cdiv(NNODES, 64), B, 0, stream>>>(h, W1, al1, ar1, feat, el, er);
    node_aggregate3<128, 4><<<cdiv(NNODES, 4), B, 0, stream>>>(rowptr, csr_src, el, er, feat, b1, x2, 1);

    // ---- layer 2 (H=4, D=32, DOUT=128) ----
    gemm_attn_rt2<64, 128, 4><<<cdiv(NNODES, 64), B, 0, stream>>>(x2, W2, al2, ar2, feat, el, er);
    node_aggregate3<128, 4><<<cdiv(NNODES, 4), B, 0, stream>>>(rowptr, csr_src, el, er, feat, b2, x3, 1);

    // ---- layer 3 (H=1, D=64, DOUT=64) ----
    gemm_attn_rt2<64, 64, 1><<<cdiv(NNODES, 64), B, 0, stream>>>(x3, W3, al3, ar3, feat, el, er);
    node_aggregate3<64, 1><<<cdiv(NNODES, 4), B, 0, stream>>>(rowptr, csr_src, el, er, feat, b3, (float*)d_out, 0);
}